// Round 7
// baseline (397.116 us; speedup 1.0000x reference)
//
#include <hip/hip_runtime.h>
#include <cstdint>

#define NNODES 10000
#define FDIM 128
#define MAXDEG 192
#define NPB 157                            // nodes per scan block
#define SCANBLK 64                         // 64 x 157 = 10048 >= 10000

typedef _Float16 h2v  __attribute__((ext_vector_type(2)));
typedef _Float16 f16x8 __attribute__((ext_vector_type(8)));
typedef float    f32x4 __attribute__((ext_vector_type(4)));

// Module-owned scratch (BSS, zero at load) — no d_ws dependence.
// g_cnt/g_bkt are FULLY REWRITTEN by prep every call (no invariant needed).
// Row NNODES of g_xh/g_h1h is a SENTINEL ZERO row (never written): gather
// batches are sentinel-padded to full 32-edge batches.
__device__ __align__(16)  int            g_cnt[NNODES];          // degree (clamped)
__device__ __align__(16)  unsigned short g_bkt[NNODES * MAXDEG]; // u16 src lists, 3.84 MB
__device__ __align__(256) unsigned g_xh [(NNODES + 1) * FDIM / 2]; // x  fp16x2
__device__ __align__(256) unsigned g_h1h[(NNODES + 1) * FDIM / 2]; // h1 fp16x2
__device__ __align__(16)  unsigned g_wf[2 * 8192];        // W1/W2 pre-packed B-frags

__device__ inline h2v as_h2(unsigned u) { return __builtin_bit_cast(h2v, u); }
__device__ inline unsigned as_u(h2v v) { return __builtin_bit_cast(unsigned, v); }
__device__ inline unsigned pack_f16x2(float a, float b) {
  h2v v; v[0] = (_Float16)a; v[1] = (_Float16)b;
  return as_u(v);
}
__device__ inline void vadd4(uint4& a, const uint4& b) {   // 4x v_pk_add_f16
  a.x = as_u(as_h2(a.x) + as_h2(b.x));
  a.y = as_u(as_h2(a.y) + as_h2(b.y));
  a.z = as_u(as_h2(a.z) + as_h2(b.z));
  a.w = as_u(as_h2(a.w) + as_h2(b.w));
}

// ---------------- prep: LDS-binned bucket build + cast + W pre-pack -------
// Scan blocks (0..63): block owns nodes [bid*157, +157). Streams the dst
// array (8-deep unrolled coalesced loads), bins src as u16 into LDS with
// LDS atomics, then writes g_cnt + g_bkt DENSE and COALESCED. This replaces
// 640k scattered 4B global stores (whose ~40 MB of partial-line evictions
// at ~1 TB/s were prep's 42 us) and all global atomics.
// Cast blocks (64..688): x -> fp16x2, float4-granular.
// Wpack blocks (689..696): W1/W2 into MFMA B-fragment dword layout.
__global__ __launch_bounds__(512) void prep_kernel(
    const float* __restrict__ x, const int* __restrict__ ei,
    const float* __restrict__ w1, const float* __restrict__ w2,
    int E_) {
  __shared__ int lcnt[NPB];
  __shared__ __align__(16) unsigned short lbkt[NPB * MAXDEG];  // 60.3 KB

  const int bid = blockIdx.x, tid = threadIdx.x;
  if (bid < SCANBLK) {
    const int lo = bid * NPB;
    const int nn = (NNODES - lo < NPB) ? (NNODES - lo) : NPB;
    for (int i = tid; i < NPB; i += 512) lcnt[i] = 0;
    __syncthreads();

    const int iters = (E_ + 511) >> 9;
    for (int it = 0; it < iters; it += 8) {
      int dv[8];
#pragma unroll
      for (int k = 0; k < 8; ++k) {        // 8 coalesced dst loads in flight
        int e = (it + k) * 512 + tid;
        dv[k] = (e < E_) ? ei[E_ + e] : -1;
      }
#pragma unroll
      for (int k = 0; k < 8; ++k) {
        unsigned rel = (unsigned)(dv[k] - lo);
        if (rel < (unsigned)nn) {
          int e = (it + k) * 512 + tid;
          int s = ei[e];                   // src only for hit lanes
          int p = atomicAdd(&lcnt[rel], 1);
          if (p < MAXDEG) lbkt[rel * MAXDEG + p] = (unsigned short)s;
        }
      }
    }
    __syncthreads();

    // dense writeout: counts (clamped) + buckets as uint4 (24 per node)
    for (int i = tid; i < nn; i += 512)
      g_cnt[lo + i] = (lcnt[i] > MAXDEG) ? MAXDEG : lcnt[i];
    const int nq = nn * (MAXDEG * 2 / 16);          // uint4s: 24 per node
    const uint4* srcq = (const uint4*)lbkt;
    uint4* dstq = (uint4*)(g_bkt + (size_t)lo * MAXDEG);
    for (int i = tid; i < nq; i += 512) dstq[i] = srcq[i];
  } else if (bid < SCANBLK + 625) {
    int i = (bid - SCANBLK) * 512 + tid;   // < 320000 exactly
    if (i < NNODES * 32) {                 // float4 -> fp16x2 pair (16B->8B)
      float4 v = *(const float4*)(x + 4 * (size_t)i);
      uint2 o; o.x = pack_f16x2(v.x, v.y); o.y = pack_f16x2(v.z, v.w);
      *(uint2*)(g_xh + 2 * (size_t)i) = o;
    }
  } else {
    // pack W1/W2 into the exact MFMA B-fragment dword layout once.
    // entry s -> (nk = s>>6, sl = s&63), n = nk>>2, kc = nk&3,
    // kbase = kc*32 + (sl>>4)*8, f = n*16 + (sl&15).
    int idx = (bid - SCANBLK - 625) * 512 + tid;  // 0..4095
    if (idx < 4096) {
      const float* w = (idx >= 2048) ? w2 : w1;
      int s = idx & 2047;
      int sl = s & 63, nk = s >> 6;
      int n = nk >> 2, kc = nk & 3;
      int kbase = kc * 32 + (sl >> 4) * 8;
      int f = n * 16 + (sl & 15);
      unsigned d0 = pack_f16x2(w[(size_t)(kbase + 0) * FDIM + f],
                               w[(size_t)(kbase + 1) * FDIM + f]);
      unsigned d1 = pack_f16x2(w[(size_t)(kbase + 2) * FDIM + f],
                               w[(size_t)(kbase + 3) * FDIM + f]);
      unsigned d2 = pack_f16x2(w[(size_t)(kbase + 4) * FDIM + f],
                               w[(size_t)(kbase + 5) * FDIM + f]);
      unsigned d3 = pack_f16x2(w[(size_t)(kbase + 6) * FDIM + f],
                               w[(size_t)(kbase + 7) * FDIM + f]);
      *(uint4*)(g_wf + (idx >> 11) * 8192 + 4 * s) = make_uint4(d0, d1, d2, d3);
    }
  }
}

// ---------------- fused GIN layer: 8 nodes/block, 1 node/wave -------------
// Block = 512 thr (8 waves) = 8 nodes (1250 blocks x 8 = 10000 exactly).
// Round-4 structure (best measured): contiguous-u16 index fetch into 3 regs
//   (deg<=192), then uniform full 32-edge batches of 8 dwordx4 loads in
//   flight: lane (quad q, m16) reads 16 B of row edge[4k+q]. Sentinel-padded;
//   no mid-loop index fetches. Quad partials folded by xor-16/xor-32
//   butterfly; quad-0 lanes write the A row.
// MFMA: 16x16x32_f16, A rows 8..15 zeroed (outputs discarded); wave w owns
//   feature-tile n = wave; B-fragments in registers from pre-packed g_wf.
// MODE 0: relu -> g_h1h (packed fp16x2). MODE 1: log_softmax -> out_g (fp32).
// NOTE: no min-waves clause — round-2 showed a forced low-VGPR allocation
// serializes the load batches and exposes full L2 latency per load.
template <int MODE>
__global__ __launch_bounds__(512) void gin_layer_kernel(
    const float* __restrict__ bvec,
    float* __restrict__ out_g) {
  const unsigned* __restrict__ xh = (MODE == 0) ? g_xh : g_h1h;

  __shared__ __align__(16) unsigned al[16 * 68];   // A tile 16 x 64 dw (+4 pad)
  __shared__ __align__(16) unsigned cfu[8 * 132];  // epilogue scratch (8 rows)

  const int tid = threadIdx.x;
  const int wave = tid >> 6, lane = tid & 63;
  const int quad = lane >> 4, m16 = lane & 15;
  const int node0 = blockIdx.x * 8;
  const int myn = node0 + wave;            // this wave's node

  // ---- B-fragments straight to registers (L2-resident, pre-packed) ----
  uint4 bf[4];
  {
    const unsigned* wfp = g_wf + (MODE ? 8192 : 0);
#pragma unroll
    for (int kc = 0; kc < 4; ++kc)
      bf[kc] = *(const uint4*)(wfp + ((wave * 4 + kc) * 64 + lane) * 4);
  }
  const float bb = bvec[wave * 16 + m16];

  // zero A rows 8..15 (MFMA reads 16 rows; only 8 valid)
  for (int i2 = tid; i2 < 8 * 68; i2 += 512) al[8 * 68 + i2] = 0;

  // ---- prologue: self row + degree ----
  uint4 self4 = *(const uint4*)(xh + (size_t)myn * 64 + (m16 << 2));
  const int deg = g_cnt[myn];              // clamped to MAXDEG by prep

  // ---- fetch ALL edge indices up-front: contiguous u16 list, 3 regs ----
  const unsigned short* nb16 = g_bkt + (size_t)myn * MAXDEG;
  int idxr[3];
#pragma unroll
  for (int r = 0; r < 3; ++r) {
    int g = r * 64 + lane;
    idxr[r] = (g < deg) ? (int)nb16[g] : NNODES;   // sentinel zero row
  }

  // ---- gather: uniform full batches of 8 dwordx4 loads (32 edges) ----
  h2v a0 = as_h2(0u), a1 = as_h2(0u), a2 = as_h2(0u), a3 = as_h2(0u);
  const int nbat = (deg + 31) >> 5;        // ceil(deg/32), <= 6
  for (int bt = 0; bt < nbat; ++bt) {
    const int r = bt >> 1;
    const int src = (r == 0) ? idxr[0] : ((r == 1) ? idxr[1] : idxr[2]);
    const int base = (bt & 1) << 5;
    uint4 t[8];
#pragma unroll
    for (int k = 0; k < 8; ++k) {
      int e = __builtin_amdgcn_ds_bpermute((base + 4 * k + quad) << 2, src);
      t[k] = *(const uint4*)(xh + (unsigned)((e << 6) | (m16 << 2)));
    }
#pragma unroll
    for (int st2 = 1; st2 < 8; st2 <<= 1)
#pragma unroll
      for (int k = 0; k < 8; k += 2 * st2) vadd4(t[k], t[k + st2]);
    a0 += as_h2(t[0].x); a1 += as_h2(t[0].y);
    a2 += as_h2(t[0].z); a3 += as_h2(t[0].w);
  }

  // fold the 4 quad partials (xor-16 then xor-32 butterfly)
  int rr;
  rr = __shfl_xor((int)as_u(a0), 16, 64); a0 += as_h2((unsigned)rr);
  rr = __shfl_xor((int)as_u(a0), 32, 64); a0 += as_h2((unsigned)rr);
  rr = __shfl_xor((int)as_u(a1), 16, 64); a1 += as_h2((unsigned)rr);
  rr = __shfl_xor((int)as_u(a1), 32, 64); a1 += as_h2((unsigned)rr);
  rr = __shfl_xor((int)as_u(a2), 16, 64); a2 += as_h2((unsigned)rr);
  rr = __shfl_xor((int)as_u(a2), 32, 64); a2 += as_h2((unsigned)rr);
  rr = __shfl_xor((int)as_u(a3), 16, 64); a3 += as_h2((unsigned)rr);
  rr = __shfl_xor((int)as_u(a3), 32, 64); a3 += as_h2((unsigned)rr);
  // (1+eps)*x self term, added once after the fold
  a0 += as_h2(self4.x); a1 += as_h2(self4.y);
  a2 += as_h2(self4.z); a3 += as_h2(self4.w);
  if (quad == 0)
    *(uint4*)(al + wave * 68 + (m16 << 2)) =
        make_uint4(as_u(a0), as_u(a1), as_u(a2), as_u(a3));
  __syncthreads();                         // A tile visible to all waves

  // ---- MFMA: ntile n = wave, B from registers ----
  uint4 af[4];
#pragma unroll
  for (int kc = 0; kc < 4; ++kc)
    af[kc] = *(const uint4*)(al + m16 * 68 + kc * 16 + quad * 4);

  const int n = wave;
  f32x4 acc = {0.f, 0.f, 0.f, 0.f};
#pragma unroll
  for (int kc = 0; kc < 4; ++kc)
    acc = __builtin_amdgcn_mfma_f32_16x16x32_f16(
            __builtin_bit_cast(f16x8, af[kc]),
            __builtin_bit_cast(f16x8, bf[kc]), acc, 0, 0, 0);

  // ---- epilogue: D col=m16(+16n), row=quad*4+reg; rows 0..7 valid ----
  if (MODE == 0) {
    // relu + fp16 pack: rows padded to 136 halves for bank spread
    _Float16* ch = (_Float16*)cfu;
    const int f = n * 16 + m16;
    if (quad < 2) {
#pragma unroll
      for (int reg = 0; reg < 4; ++reg)
        ch[(quad * 4 + reg) * 136 + f] = (_Float16)fmaxf(acc[reg] + bb, 0.f);
    }
    __syncthreads();
    if (tid < 256) {
      const int row = tid >> 5, c2 = (tid & 31) * 2;
      uint2 v = *(const uint2*)(cfu + row * 68 + c2);
      *(uint2*)(&g_h1h[(size_t)(node0 + row) * 64 + c2]) = v;
    }
  } else {
    // log_softmax: vals to LDS fp32 (rows padded to 132 floats)
    float* cf = (float*)cfu;
    const int f = n * 16 + m16;
    if (quad < 2) {
#pragma unroll
      for (int reg = 0; reg < 4; ++reg)
        cf[(quad * 4 + reg) * 132 + f] = acc[reg] + bb;
    }
    __syncthreads();
    if (tid < 256) {
      const int row = tid >> 5, li = tid & 31;   // 32 threads per row
      const float* base = cf + row * 132 + li * 4;
      float4 a4 = *(const float4*)(base);
      float mx = fmaxf(fmaxf(a4.x, a4.y), fmaxf(a4.z, a4.w));
#pragma unroll
      for (int off = 16; off >= 1; off >>= 1)
        mx = fmaxf(mx, __shfl_xor(mx, off, 64));   // within 32-lane half-wave
      float s = (__expf(a4.x - mx) + __expf(a4.y - mx))
              + (__expf(a4.z - mx) + __expf(a4.w - mx));
#pragma unroll
      for (int off = 16; off >= 1; off >>= 1)
        s += __shfl_xor(s, off, 64);
      const float ls = mx + __logf(s);
      float* orow = out_g + (size_t)(node0 + row) * FDIM + li * 4;
      *(float4*)(orow) = make_float4(a4.x - ls, a4.y - ls, a4.z - ls, a4.w - ls);
    }
  }
}

extern "C" void kernel_launch(void* const* d_in, const int* in_sizes, int n_in,
                              void* d_out, int out_size, void* d_ws, size_t ws_size,
                              hipStream_t stream) {
  const float* x  = (const float*)d_in[0];
  const int*   ei = (const int*)d_in[1];     // int64 in reference -> int32 here
  const float* w1 = (const float*)d_in[2];
  const float* b1 = (const float*)d_in[3];
  const float* w2 = (const float*)d_in[4];
  const float* b2 = (const float*)d_in[5];
  float* out = (float*)d_out;

  const int E_ = in_sizes[1] / 2;

  // ---- prep: 64 scan + 625 cast + 8 wpack blocks, 512 threads each ----
  prep_kernel<<<SCANBLK + 625 + 8, 512, 0, stream>>>(x, ei, w1, w2, E_);

  // ---- layers: 1250 blocks x 8 waves x 1 node = 10000 exactly ----
  gin_layer_kernel<0><<<1250, 512, 0, stream>>>(b1, nullptr);
  gin_layer_kernel<1><<<1250, 512, 0, stream>>>(b2, out);
}

// Round 8
// 108.137 us; speedup vs baseline: 3.6723x; 3.6723x over previous
//
#include <hip/hip_runtime.h>
#include <cstdint>

#define NNODES 10000
#define FDIM 128
#define MAXDEG 192
#define NPB 157                            // nodes per bin (64 x 157 = 10048)
#define NBIN 64
#define BINCAP 16384                       // entries per coarse bin (mean ~10048)

typedef _Float16 h2v  __attribute__((ext_vector_type(2)));
typedef _Float16 f16x8 __attribute__((ext_vector_type(8)));
typedef float    f32x4 __attribute__((ext_vector_type(4)));

// Module-owned scratch (BSS, zero at load) — no d_ws dependence.
// g_binoff invariant: zero at entry to every kernel_launch (BSS first call;
// prep2 re-zeroes its own bin after consuming it, every call).
// g_cnt/g_bkt are FULLY REWRITTEN by prep2 every call.
// Row NNODES of g_xh/g_h1h is a SENTINEL ZERO row (never written): gather
// batches are sentinel-padded to full 32-edge batches.
__device__ __align__(16)  int            g_binoff[NBIN];         // coarse-bin fill
__device__ __align__(16)  unsigned       g_binbuf[NBIN * BINCAP];// packed (rel,src), 4MB
__device__ __align__(16)  int            g_cnt[NNODES];          // degree (clamped)
__device__ __align__(16)  unsigned short g_bkt[NNODES * MAXDEG]; // u16 src lists, 3.84MB
__device__ __align__(256) unsigned g_xh [(NNODES + 1) * FDIM / 2]; // x  fp16x2
__device__ __align__(256) unsigned g_h1h[(NNODES + 1) * FDIM / 2]; // h1 fp16x2
__device__ __align__(16)  unsigned g_wf[2 * 8192];        // W1/W2 pre-packed B-frags

__device__ inline h2v as_h2(unsigned u) { return __builtin_bit_cast(h2v, u); }
__device__ inline unsigned as_u(h2v v) { return __builtin_bit_cast(unsigned, v); }
__device__ inline unsigned pack_f16x2(float a, float b) {
  h2v v; v[0] = (_Float16)a; v[1] = (_Float16)b;
  return as_u(v);
}
__device__ inline void vadd4(uint4& a, const uint4& b) {   // 4x v_pk_add_f16
  a.x = as_u(as_h2(a.x) + as_h2(b.x));
  a.y = as_u(as_h2(a.y) + as_h2(b.y));
  a.z = as_u(as_h2(a.z) + as_h2(b.z));
  a.w = as_u(as_h2(a.w) + as_h2(b.w));
}

// ---------------- prep1: coarse partition + cast + W pre-pack -------------
// Edge blocks (0..PBLK-1): block owns 4096 edges (8/thread). Bin by dst/157
// into 64 coarse bins: LDS rank -> ONE global atomic per (block,bin) to
// reserve a contiguous run -> packed u32 (dst_rel<<16 | src) written as
// ~64-entry contiguous runs (full-line, single-XCD). Coalesced reads, 2.56MB
// effectively-coalesced writes — replaces round-6's 640k scattered stores
// (41MB partial-line writeback) AND round-7's 64x read amplification.
// Cast blocks: x -> fp16x2, float4-granular. Wpack: MFMA B-frag layout.
__global__ __launch_bounds__(512) void prep1_kernel(
    const float* __restrict__ x, const int* __restrict__ ei,
    const float* __restrict__ w1, const float* __restrict__ w2,
    int E_, int PBLK) {
  const int bid = blockIdx.x, tid = threadIdx.x;
  if (bid < PBLK) {
    __shared__ int lcnt[NBIN], lbase[NBIN];
    if (tid < NBIN) lcnt[tid] = 0;
    __syncthreads();
    int dv[8], sv[8], rk[8], bn[8];
#pragma unroll
    for (int k = 0; k < 8; ++k) {          // coalesced dst+src loads
      int e = bid * 4096 + k * 512 + tid;
      dv[k] = (e < E_) ? ei[E_ + e] : -1;
      sv[k] = (e < E_) ? ei[e] : 0;
    }
#pragma unroll
    for (int k = 0; k < 8; ++k) {
      if (dv[k] >= 0) {
        bn[k] = (unsigned)dv[k] / NPB;     // const-div -> magic mul
        rk[k] = atomicAdd(&lcnt[bn[k]], 1);
      }
    }
    __syncthreads();
    if (tid < NBIN && lcnt[tid] > 0)
      lbase[tid] = atomicAdd(&g_binoff[tid], lcnt[tid]);
    __syncthreads();
#pragma unroll
    for (int k = 0; k < 8; ++k) {
      if (dv[k] >= 0) {
        int pos = lbase[bn[k]] + rk[k];
        if (pos < BINCAP)
          g_binbuf[bn[k] * BINCAP + pos] =
              ((unsigned)(dv[k] - bn[k] * NPB) << 16) | (unsigned)sv[k];
      }
    }
  } else if (bid < PBLK + 625) {
    int i = (bid - PBLK) * 512 + tid;      // < 320000 exactly
    if (i < NNODES * 32) {                 // float4 -> fp16x2 pair (16B->8B)
      float4 v = *(const float4*)(x + 4 * (size_t)i);
      uint2 o; o.x = pack_f16x2(v.x, v.y); o.y = pack_f16x2(v.z, v.w);
      *(uint2*)(g_xh + 2 * (size_t)i) = o;
    }
  } else {
    // pack W1/W2 into the exact MFMA B-fragment dword layout once.
    // entry s -> (nk = s>>6, sl = s&63), n = nk>>2, kc = nk&3,
    // kbase = kc*32 + (sl>>4)*8, f = n*16 + (sl&15).
    int idx = (bid - PBLK - 625) * 512 + tid;  // 0..4095
    if (idx < 4096) {
      const float* w = (idx >= 2048) ? w2 : w1;
      int s = idx & 2047;
      int sl = s & 63, nk = s >> 6;
      int n = nk >> 2, kc = nk & 3;
      int kbase = kc * 32 + (sl >> 4) * 8;
      int f = n * 16 + (sl & 15);
      unsigned d0 = pack_f16x2(w[(size_t)(kbase + 0) * FDIM + f],
                               w[(size_t)(kbase + 1) * FDIM + f]);
      unsigned d1 = pack_f16x2(w[(size_t)(kbase + 2) * FDIM + f],
                               w[(size_t)(kbase + 3) * FDIM + f]);
      unsigned d2 = pack_f16x2(w[(size_t)(kbase + 4) * FDIM + f],
                               w[(size_t)(kbase + 5) * FDIM + f]);
      unsigned d3 = pack_f16x2(w[(size_t)(kbase + 6) * FDIM + f],
                               w[(size_t)(kbase + 7) * FDIM + f]);
      *(uint4*)(g_wf + (idx >> 11) * 8192 + 4 * s) = make_uint4(d0, d1, d2, d3);
    }
  }
}

// ---------------- prep2: bin-local u16 bucket build (no amplification) ----
// 64 blocks; block bid consumes ONLY bin bid (~10k packed entries, 40KB
// coalesced read), LDS-bins to u16 buckets, dense-coalesced writeout of
// g_cnt + g_bkt, then restores the g_binoff zero invariant.
__global__ __launch_bounds__(512) void prep2_kernel() {
  __shared__ int lcnt[NPB];
  __shared__ __align__(16) unsigned short lbkt[NPB * MAXDEG];  // 60.3 KB

  const int bid = blockIdx.x, tid = threadIdx.x;
  const int lo = bid * NPB;
  const int nn = (NNODES - lo < NPB) ? (NNODES - lo) : NPB;
  for (int i = tid; i < NPB; i += 512) lcnt[i] = 0;
  __syncthreads();

  int cnt = g_binoff[bid];
  if (cnt > BINCAP) cnt = BINCAP;
  const unsigned* buf = g_binbuf + (size_t)bid * BINCAP;
  for (int i = tid; i < cnt; i += 512) {
    unsigned p = buf[i];
    int rel = (int)(p >> 16);
    if (rel < nn) {
      int q = atomicAdd(&lcnt[rel], 1);
      if (q < MAXDEG) lbkt[rel * MAXDEG + q] = (unsigned short)(p & 0xffffu);
    }
  }
  __syncthreads();

  for (int i = tid; i < nn; i += 512)
    g_cnt[lo + i] = (lcnt[i] > MAXDEG) ? MAXDEG : lcnt[i];
  const int nq = nn * (MAXDEG / 8);        // uint4 = 8 u16; 24 per node
  const uint4* srcq = (const uint4*)lbkt;
  uint4* dstq = (uint4*)(g_bkt + (size_t)lo * MAXDEG);
  for (int i = tid; i < nq; i += 512) dstq[i] = srcq[i];
  if (tid == 0) g_binoff[bid] = 0;         // restore invariant
}

// ---------------- fused GIN layer: 8 nodes/block, 1 node/wave -------------
// Block = 512 thr (8 waves) = 8 nodes (1250 blocks x 8 = 10000 exactly).
// Round-4 structure (best measured): contiguous-u16 index fetch into 3 regs
//   (deg<=192), then uniform full 32-edge batches of 8 dwordx4 loads in
//   flight: lane (quad q, m16) reads 16 B of row edge[4k+q]. Sentinel-padded;
//   no mid-loop index fetches. Quad partials folded by xor-16/xor-32
//   butterfly; quad-0 lanes write the A row.
// MFMA: 16x16x32_f16, A rows 8..15 zeroed (outputs discarded); wave w owns
//   feature-tile n = wave; B-fragments in registers from pre-packed g_wf.
// MODE 0: relu -> g_h1h (packed fp16x2). MODE 1: log_softmax -> out_g (fp32).
template <int MODE>
__global__ __launch_bounds__(512) void gin_layer_kernel(
    const float* __restrict__ bvec,
    float* __restrict__ out_g) {
  const unsigned* __restrict__ xh = (MODE == 0) ? g_xh : g_h1h;

  __shared__ __align__(16) unsigned al[16 * 68];   // A tile 16 x 64 dw (+4 pad)
  __shared__ __align__(16) unsigned cfu[8 * 132];  // epilogue scratch (8 rows)

  const int tid = threadIdx.x;
  const int wave = tid >> 6, lane = tid & 63;
  const int quad = lane >> 4, m16 = lane & 15;
  const int node0 = blockIdx.x * 8;
  const int myn = node0 + wave;            // this wave's node

  // ---- B-fragments straight to registers (L2-resident, pre-packed) ----
  uint4 bf[4];
  {
    const unsigned* wfp = g_wf + (MODE ? 8192 : 0);
#pragma unroll
    for (int kc = 0; kc < 4; ++kc)
      bf[kc] = *(const uint4*)(wfp + ((wave * 4 + kc) * 64 + lane) * 4);
  }
  const float bb = bvec[wave * 16 + m16];

  // zero A rows 8..15 (MFMA reads 16 rows; only 8 valid)
  for (int i2 = tid; i2 < 8 * 68; i2 += 512) al[8 * 68 + i2] = 0;

  // ---- prologue: self row + degree ----
  uint4 self4 = *(const uint4*)(xh + (size_t)myn * 64 + (m16 << 2));
  const int deg = g_cnt[myn];              // clamped to MAXDEG by prep2

  // ---- fetch ALL edge indices up-front: contiguous u16 list, 3 regs ----
  const unsigned short* nb16 = g_bkt + (size_t)myn * MAXDEG;
  int idxr[3];
#pragma unroll
  for (int r = 0; r < 3; ++r) {
    int g = r * 64 + lane;
    idxr[r] = (g < deg) ? (int)nb16[g] : NNODES;   // sentinel zero row
  }

  // ---- gather: uniform full batches of 8 dwordx4 loads (32 edges) ----
  h2v a0 = as_h2(0u), a1 = as_h2(0u), a2 = as_h2(0u), a3 = as_h2(0u);
  const int nbat = (deg + 31) >> 5;        // ceil(deg/32), <= 6
  for (int bt = 0; bt < nbat; ++bt) {
    const int r = bt >> 1;
    const int src = (r == 0) ? idxr[0] : ((r == 1) ? idxr[1] : idxr[2]);
    const int base = (bt & 1) << 5;
    uint4 t[8];
#pragma unroll
    for (int k = 0; k < 8; ++k) {
      int e = __builtin_amdgcn_ds_bpermute((base + 4 * k + quad) << 2, src);
      t[k] = *(const uint4*)(xh + (unsigned)((e << 6) | (m16 << 2)));
    }
#pragma unroll
    for (int st2 = 1; st2 < 8; st2 <<= 1)
#pragma unroll
      for (int k = 0; k < 8; k += 2 * st2) vadd4(t[k], t[k + st2]);
    a0 += as_h2(t[0].x); a1 += as_h2(t[0].y);
    a2 += as_h2(t[0].z); a3 += as_h2(t[0].w);
  }

  // fold the 4 quad partials (xor-16 then xor-32 butterfly)
  int rr;
  rr = __shfl_xor((int)as_u(a0), 16, 64); a0 += as_h2((unsigned)rr);
  rr = __shfl_xor((int)as_u(a0), 32, 64); a0 += as_h2((unsigned)rr);
  rr = __shfl_xor((int)as_u(a1), 16, 64); a1 += as_h2((unsigned)rr);
  rr = __shfl_xor((int)as_u(a1), 32, 64); a1 += as_h2((unsigned)rr);
  rr = __shfl_xor((int)as_u(a2), 16, 64); a2 += as_h2((unsigned)rr);
  rr = __shfl_xor((int)as_u(a2), 32, 64); a2 += as_h2((unsigned)rr);
  rr = __shfl_xor((int)as_u(a3), 16, 64); a3 += as_h2((unsigned)rr);
  rr = __shfl_xor((int)as_u(a3), 32, 64); a3 += as_h2((unsigned)rr);
  // (1+eps)*x self term, added once after the fold
  a0 += as_h2(self4.x); a1 += as_h2(self4.y);
  a2 += as_h2(self4.z); a3 += as_h2(self4.w);
  if (quad == 0)
    *(uint4*)(al + wave * 68 + (m16 << 2)) =
        make_uint4(as_u(a0), as_u(a1), as_u(a2), as_u(a3));
  __syncthreads();                         // A tile visible to all waves

  // ---- MFMA: ntile n = wave, B from registers ----
  uint4 af[4];
#pragma unroll
  for (int kc = 0; kc < 4; ++kc)
    af[kc] = *(const uint4*)(al + m16 * 68 + kc * 16 + quad * 4);

  const int n = wave;
  f32x4 acc = {0.f, 0.f, 0.f, 0.f};
#pragma unroll
  for (int kc = 0; kc < 4; ++kc)
    acc = __builtin_amdgcn_mfma_f32_16x16x32_f16(
            __builtin_bit_cast(f16x8, af[kc]),
            __builtin_bit_cast(f16x8, bf[kc]), acc, 0, 0, 0);

  // ---- epilogue: D col=m16(+16n), row=quad*4+reg; rows 0..7 valid ----
  if (MODE == 0) {
    // relu + fp16 pack: rows padded to 136 halves for bank spread
    _Float16* ch = (_Float16*)cfu;
    const int f = n * 16 + m16;
    if (quad < 2) {
#pragma unroll
      for (int reg = 0; reg < 4; ++reg)
        ch[(quad * 4 + reg) * 136 + f] = (_Float16)fmaxf(acc[reg] + bb, 0.f);
    }
    __syncthreads();
    if (tid < 256) {
      const int row = tid >> 5, c2 = (tid & 31) * 2;
      uint2 v = *(const uint2*)(cfu + row * 68 + c2);
      *(uint2*)(&g_h1h[(size_t)(node0 + row) * 64 + c2]) = v;
    }
  } else {
    // log_softmax: vals to LDS fp32 (rows padded to 132 floats)
    float* cf = (float*)cfu;
    const int f = n * 16 + m16;
    if (quad < 2) {
#pragma unroll
      for (int reg = 0; reg < 4; ++reg)
        cf[(quad * 4 + reg) * 132 + f] = acc[reg] + bb;
    }
    __syncthreads();
    if (tid < 256) {
      const int row = tid >> 5, li = tid & 31;   // 32 threads per row
      const float* base = cf + row * 132 + li * 4;
      float4 a4 = *(const float4*)(base);
      float mx = fmaxf(fmaxf(a4.x, a4.y), fmaxf(a4.z, a4.w));
#pragma unroll
      for (int off = 16; off >= 1; off >>= 1)
        mx = fmaxf(mx, __shfl_xor(mx, off, 64));   // within 32-lane half-wave
      float s = (__expf(a4.x - mx) + __expf(a4.y - mx))
              + (__expf(a4.z - mx) + __expf(a4.w - mx));
#pragma unroll
      for (int off = 16; off >= 1; off >>= 1)
        s += __shfl_xor(s, off, 64);
      const float ls = mx + __logf(s);
      float* orow = out_g + (size_t)(node0 + row) * FDIM + li * 4;
      *(float4*)(orow) = make_float4(a4.x - ls, a4.y - ls, a4.z - ls, a4.w - ls);
    }
  }
}

extern "C" void kernel_launch(void* const* d_in, const int* in_sizes, int n_in,
                              void* d_out, int out_size, void* d_ws, size_t ws_size,
                              hipStream_t stream) {
  const float* x  = (const float*)d_in[0];
  const int*   ei = (const int*)d_in[1];     // int64 in reference -> int32 here
  const float* w1 = (const float*)d_in[2];
  const float* b1 = (const float*)d_in[3];
  const float* w2 = (const float*)d_in[4];
  const float* b2 = (const float*)d_in[5];
  float* out = (float*)d_out;

  const int E_ = in_sizes[1] / 2;
  const int PBLK = (E_ + 4095) / 4096;     // 157 edge blocks

  // ---- prep1: coarse partition + cast + wpack (binoff zero by invariant) ----
  prep1_kernel<<<PBLK + 625 + 8, 512, 0, stream>>>(x, ei, w1, w2, E_, PBLK);
  // ---- prep2: bin-local bucket build (restores binoff invariant) ----
  prep2_kernel<<<NBIN, 512, 0, stream>>>();

  // ---- layers: 1250 blocks x 8 waves x 1 node = 10000 exactly ----
  gin_layer_kernel<0><<<1250, 512, 0, stream>>>(b1, nullptr);
  gin_layer_kernel<1><<<1250, 512, 0, stream>>>(b2, out);
}

// Round 9
// 105.375 us; speedup vs baseline: 3.7686x; 1.0262x over previous
//
#include <hip/hip_runtime.h>
#include <cstdint>

#define NNODES 10000
#define FDIM 128
#define MAXDEG 192
#define NPB 79                             // nodes per bin (128 x 79 = 10112)
#define NBIN 128
#define BINCAP 6144                        // entries per coarse bin (mean ~5056)
#define SENT16 0x27102710u                 // two u16 sentinels (10000 = zero row)

typedef _Float16 h2v  __attribute__((ext_vector_type(2)));
typedef _Float16 f16x8 __attribute__((ext_vector_type(8)));
typedef float    f32x4 __attribute__((ext_vector_type(4)));

// Module-owned scratch (BSS, zero at load) — no d_ws dependence.
// g_binoff invariant: zero at entry to every kernel_launch (BSS first call;
// prep2 scan blocks re-zero their own bin after consuming it, every call).
// g_cnt/g_bkt are FULLY REWRITTEN by prep2 every call; bucket rows are
// SENTINEL-PADDED to MAXDEG (sentinel = NNODES = zero feature row), so the
// gin layers load index registers UNPREDICATED (no deg dependency).
__device__ __align__(16)  int            g_binoff[NBIN];         // coarse-bin fill
__device__ __align__(16)  unsigned       g_binbuf[NBIN * BINCAP];// packed (rel,src), 3MB
__device__ __align__(16)  int            g_cnt[NNODES];          // degree (clamped)
__device__ __align__(16)  unsigned short g_bkt[NNODES * MAXDEG]; // u16 src lists, 3.84MB
__device__ __align__(256) unsigned g_xh [(NNODES + 1) * FDIM / 2]; // x  fp16x2
__device__ __align__(256) unsigned g_h1h[(NNODES + 1) * FDIM / 2]; // h1 fp16x2
__device__ __align__(16)  unsigned g_wf[2 * 8192];        // W1/W2 pre-packed B-frags

__device__ inline h2v as_h2(unsigned u) { return __builtin_bit_cast(h2v, u); }
__device__ inline unsigned as_u(h2v v) { return __builtin_bit_cast(unsigned, v); }
__device__ inline unsigned pack_f16x2(float a, float b) {
  h2v v; v[0] = (_Float16)a; v[1] = (_Float16)b;
  return as_u(v);
}
__device__ inline void vadd4(uint4& a, const uint4& b) {   // 4x v_pk_add_f16
  a.x = as_u(as_h2(a.x) + as_h2(b.x));
  a.y = as_u(as_h2(a.y) + as_h2(b.y));
  a.z = as_u(as_h2(a.z) + as_h2(b.z));
  a.w = as_u(as_h2(a.w) + as_h2(b.w));
}

// ---------------- prep1: coarse partition ONLY (157 blocks) ---------------
// Block owns 4096 edges (8/thread). Bin by dst/79 into 128 coarse bins:
// LDS rank -> ONE global atomic per (block,bin) reserves a contiguous run
// -> packed u32 (dst_rel<<16 | src) written as ~32-entry contiguous runs.
// Coalesced reads, 2.56MB effectively-coalesced writes.
__global__ __launch_bounds__(512) void prep1_kernel(
    const int* __restrict__ ei, int E_) {
  __shared__ int lcnt[NBIN], lbase[NBIN];
  const int bid = blockIdx.x, tid = threadIdx.x;
  if (tid < NBIN) lcnt[tid] = 0;
  __syncthreads();
  int dv[8], sv[8], rk[8], bn[8];
#pragma unroll
  for (int k = 0; k < 8; ++k) {            // coalesced dst+src loads
    int e = bid * 4096 + k * 512 + tid;
    dv[k] = (e < E_) ? ei[E_ + e] : -1;
    sv[k] = (e < E_) ? ei[e] : 0;
  }
#pragma unroll
  for (int k = 0; k < 8; ++k) {
    if (dv[k] >= 0) {
      bn[k] = (unsigned)dv[k] / NPB;       // const-div -> magic mul
      rk[k] = atomicAdd(&lcnt[bn[k]], 1);
    }
  }
  __syncthreads();
  if (tid < NBIN && lcnt[tid] > 0)
    lbase[tid] = atomicAdd(&g_binoff[tid], lcnt[tid]);
  __syncthreads();
#pragma unroll
  for (int k = 0; k < 8; ++k) {
    if (dv[k] >= 0) {
      int pos = lbase[bn[k]] + rk[k];
      if (pos < BINCAP)
        g_binbuf[bn[k] * BINCAP + pos] =
            ((unsigned)(dv[k] - bn[k] * NPB) << 16) | (unsigned)sv[k];
    }
  }
}

// ---------------- prep2: bin-local bucket build + cast + W pre-pack -------
// Scan blocks (0..127) FIRST in dispatch order: block bid consumes ONLY bin
// bid (~5k packed entries, 20KB coalesced read), LDS-bins to SENTINEL-
// PREFILLED u16 buckets (rows padded to MAXDEG with 10000 = zero row),
// dense-coalesced writeout of g_cnt + g_bkt, restores g_binoff invariant.
// Cast blocks (128..752) run CONCURRENTLY and hide the scan tail (round-8's
// 64-block prep2 ran at 25% CU occupancy with nothing co-scheduled).
// Wpack blocks (753..760): W1/W2 into MFMA B-fragment dword layout.
__global__ __launch_bounds__(512) void prep2_kernel(
    const float* __restrict__ x,
    const float* __restrict__ w1, const float* __restrict__ w2) {
  const int bid = blockIdx.x, tid = threadIdx.x;
  if (bid < NBIN) {
    __shared__ int lcnt[NPB];
    __shared__ __align__(16) unsigned short lbkt[NPB * MAXDEG];  // 30.3 KB
    const int lo = bid * NPB;
    const int nnr = NNODES - lo;
    const int nn = (nnr < 0) ? 0 : ((nnr < NPB) ? nnr : NPB);
    for (int i = tid; i < NPB; i += 512) lcnt[i] = 0;
    {                                      // sentinel pre-fill (pads rows)
      const uint4 sent = make_uint4(SENT16, SENT16, SENT16, SENT16);
      uint4* lb4 = (uint4*)lbkt;
      for (int i = tid; i < NPB * MAXDEG / 8; i += 512) lb4[i] = sent;
    }
    __syncthreads();

    int cnt = g_binoff[bid];
    if (cnt > BINCAP) cnt = BINCAP;
    const unsigned* buf = g_binbuf + (size_t)bid * BINCAP;
    for (int i = tid; i < cnt; i += 512) {
      unsigned p = buf[i];
      int rel = (int)(p >> 16);
      if (rel < nn) {
        int q = atomicAdd(&lcnt[rel], 1);
        if (q < MAXDEG) lbkt[rel * MAXDEG + q] = (unsigned short)(p & 0xffffu);
      }
    }
    __syncthreads();

    for (int i = tid; i < nn; i += 512)
      g_cnt[lo + i] = (lcnt[i] > MAXDEG) ? MAXDEG : lcnt[i];
    const int nq = nn * (MAXDEG / 8);      // uint4 = 8 u16; 24 per node
    const uint4* srcq = (const uint4*)lbkt;
    uint4* dstq = (uint4*)(g_bkt + (size_t)lo * MAXDEG);
    for (int i = tid; i < nq; i += 512) dstq[i] = srcq[i];
    if (tid == 0) g_binoff[bid] = 0;       // restore invariant
  } else if (bid < NBIN + 625) {
    int i = (bid - NBIN) * 512 + tid;      // < 320000 exactly
    if (i < NNODES * 32) {                 // float4 -> fp16x2 pair (16B->8B)
      float4 v = *(const float4*)(x + 4 * (size_t)i);
      uint2 o; o.x = pack_f16x2(v.x, v.y); o.y = pack_f16x2(v.z, v.w);
      *(uint2*)(g_xh + 2 * (size_t)i) = o;
    }
  } else {
    // pack W1/W2 into the exact MFMA B-fragment dword layout once.
    // entry s -> (nk = s>>6, sl = s&63), n = nk>>2, kc = nk&3,
    // kbase = kc*32 + (sl>>4)*8, f = n*16 + (sl&15).
    int idx = (bid - NBIN - 625) * 512 + tid;  // 0..4095
    if (idx < 4096) {
      const float* w = (idx >= 2048) ? w2 : w1;
      int s = idx & 2047;
      int sl = s & 63, nk = s >> 6;
      int n = nk >> 2, kc = nk & 3;
      int kbase = kc * 32 + (sl >> 4) * 8;
      int f = n * 16 + (sl & 15);
      unsigned d0 = pack_f16x2(w[(size_t)(kbase + 0) * FDIM + f],
                               w[(size_t)(kbase + 1) * FDIM + f]);
      unsigned d1 = pack_f16x2(w[(size_t)(kbase + 2) * FDIM + f],
                               w[(size_t)(kbase + 3) * FDIM + f]);
      unsigned d2 = pack_f16x2(w[(size_t)(kbase + 4) * FDIM + f],
                               w[(size_t)(kbase + 5) * FDIM + f]);
      unsigned d3 = pack_f16x2(w[(size_t)(kbase + 6) * FDIM + f],
                               w[(size_t)(kbase + 7) * FDIM + f]);
      *(uint4*)(g_wf + (idx >> 11) * 8192 + 4 * s) = make_uint4(d0, d1, d2, d3);
    }
  }
}

// ---------------- fused GIN layer: 8 nodes/block, 1 node/wave -------------
// Block = 512 thr (8 waves) = 8 nodes (1250 blocks x 8 = 10000 exactly).
// Round-4-proven gather, with the chain head cut: index registers are
//   loaded UNPREDICATED (bucket rows sentinel-padded by prep2), so the 3
//   u16 index loads issue at kernel start IN PARALLEL with the g_cnt load
//   (deg only gates the batch-count branch, which resolves while the
//   gather loads are in flight). Then uniform full 32-edge batches of
//   8 dwordx4 loads: lane (quad q, m16) reads 16 B of row edge[4k+q].
//   Quad partials folded by xor-16/xor-32 butterfly; quad-0 writes A row.
// MFMA: 16x16x32_f16, A rows 8..15 zeroed (outputs discarded); wave w owns
//   feature-tile n = wave; B-fragments in registers from pre-packed g_wf.
// MODE 0: relu -> g_h1h (packed fp16x2). MODE 1: log_softmax -> out_g (fp32).
template <int MODE>
__global__ __launch_bounds__(512) void gin_layer_kernel(
    const float* __restrict__ bvec,
    float* __restrict__ out_g) {
  const unsigned* __restrict__ xh = (MODE == 0) ? g_xh : g_h1h;

  __shared__ __align__(16) unsigned al[16 * 68];   // A tile 16 x 64 dw (+4 pad)
  __shared__ __align__(16) unsigned cfu[8 * 132];  // epilogue scratch (8 rows)

  const int tid = threadIdx.x;
  const int wave = tid >> 6, lane = tid & 63;
  const int quad = lane >> 4, m16 = lane & 15;
  const int node0 = blockIdx.x * 8;
  const int myn = node0 + wave;            // this wave's node

  // ---- head loads, all independent, issue immediately ----
  const unsigned short* nb16 = g_bkt + (size_t)myn * MAXDEG;
  int idxr[3];
#pragma unroll
  for (int r = 0; r < 3; ++r)
    idxr[r] = (int)nb16[r * 64 + lane];    // unpredicated (sentinel-padded)
  const int deg = g_cnt[myn];              // clamped to MAXDEG by prep2
  uint4 self4 = *(const uint4*)(xh + (size_t)myn * 64 + (m16 << 2));

  // ---- B-fragments straight to registers (L2-resident, pre-packed) ----
  uint4 bf[4];
  {
    const unsigned* wfp = g_wf + (MODE ? 8192 : 0);
#pragma unroll
    for (int kc = 0; kc < 4; ++kc)
      bf[kc] = *(const uint4*)(wfp + ((wave * 4 + kc) * 64 + lane) * 4);
  }
  const float bb = bvec[wave * 16 + m16];

  // zero A rows 8..15 (MFMA reads 16 rows; only 8 valid)
  for (int i2 = tid; i2 < 8 * 68; i2 += 512) al[8 * 68 + i2] = 0;

  // ---- gather: uniform full batches of 8 dwordx4 loads (32 edges) ----
  h2v a0 = as_h2(0u), a1 = as_h2(0u), a2 = as_h2(0u), a3 = as_h2(0u);
  const int nbat = (deg + 31) >> 5;        // ceil(deg/32), <= 6
  for (int bt = 0; bt < nbat; ++bt) {
    const int r = bt >> 1;
    const int src = (r == 0) ? idxr[0] : ((r == 1) ? idxr[1] : idxr[2]);
    const int base = (bt & 1) << 5;
    uint4 t[8];
#pragma unroll
    for (int k = 0; k < 8; ++k) {
      int e = __builtin_amdgcn_ds_bpermute((base + 4 * k + quad) << 2, src);
      t[k] = *(const uint4*)(xh + (unsigned)((e << 6) | (m16 << 2)));
    }
#pragma unroll
    for (int st2 = 1; st2 < 8; st2 <<= 1)
#pragma unroll
      for (int k = 0; k < 8; k += 2 * st2) vadd4(t[k], t[k + st2]);
    a0 += as_h2(t[0].x); a1 += as_h2(t[0].y);
    a2 += as_h2(t[0].z); a3 += as_h2(t[0].w);
  }

  // fold the 4 quad partials (xor-16 then xor-32 butterfly)
  int rr;
  rr = __shfl_xor((int)as_u(a0), 16, 64); a0 += as_h2((unsigned)rr);
  rr = __shfl_xor((int)as_u(a0), 32, 64); a0 += as_h2((unsigned)rr);
  rr = __shfl_xor((int)as_u(a1), 16, 64); a1 += as_h2((unsigned)rr);
  rr = __shfl_xor((int)as_u(a1), 32, 64); a1 += as_h2((unsigned)rr);
  rr = __shfl_xor((int)as_u(a2), 16, 64); a2 += as_h2((unsigned)rr);
  rr = __shfl_xor((int)as_u(a2), 32, 64); a2 += as_h2((unsigned)rr);
  rr = __shfl_xor((int)as_u(a3), 16, 64); a3 += as_h2((unsigned)rr);
  rr = __shfl_xor((int)as_u(a3), 32, 64); a3 += as_h2((unsigned)rr);
  // (1+eps)*x self term, added once after the fold
  a0 += as_h2(self4.x); a1 += as_h2(self4.y);
  a2 += as_h2(self4.z); a3 += as_h2(self4.w);
  if (quad == 0)
    *(uint4*)(al + wave * 68 + (m16 << 2)) =
        make_uint4(as_u(a0), as_u(a1), as_u(a2), as_u(a3));
  __syncthreads();                         // A tile visible to all waves

  // ---- MFMA: ntile n = wave, B from registers ----
  uint4 af[4];
#pragma unroll
  for (int kc = 0; kc < 4; ++kc)
    af[kc] = *(const uint4*)(al + m16 * 68 + kc * 16 + quad * 4);

  const int n = wave;
  f32x4 acc = {0.f, 0.f, 0.f, 0.f};
#pragma unroll
  for (int kc = 0; kc < 4; ++kc)
    acc = __builtin_amdgcn_mfma_f32_16x16x32_f16(
            __builtin_bit_cast(f16x8, af[kc]),
            __builtin_bit_cast(f16x8, bf[kc]), acc, 0, 0, 0);

  // ---- epilogue: D col=m16(+16n), row=quad*4+reg; rows 0..7 valid ----
  if (MODE == 0) {
    // relu + fp16 pack: rows padded to 136 halves for bank spread
    _Float16* ch = (_Float16*)cfu;
    const int f = n * 16 + m16;
    if (quad < 2) {
#pragma unroll
      for (int reg = 0; reg < 4; ++reg)
        ch[(quad * 4 + reg) * 136 + f] = (_Float16)fmaxf(acc[reg] + bb, 0.f);
    }
    __syncthreads();
    if (tid < 256) {
      const int row = tid >> 5, c2 = (tid & 31) * 2;
      uint2 v = *(const uint2*)(cfu + row * 68 + c2);
      *(uint2*)(&g_h1h[(size_t)(node0 + row) * 64 + c2]) = v;
    }
  } else {
    // log_softmax: vals to LDS fp32 (rows padded to 132 floats)
    float* cf = (float*)cfu;
    const int f = n * 16 + m16;
    if (quad < 2) {
#pragma unroll
      for (int reg = 0; reg < 4; ++reg)
        cf[(quad * 4 + reg) * 132 + f] = acc[reg] + bb;
    }
    __syncthreads();
    if (tid < 256) {
      const int row = tid >> 5, li = tid & 31;   // 32 threads per row
      const float* base = cf + row * 132 + li * 4;
      float4 a4 = *(const float4*)(base);
      float mx = fmaxf(fmaxf(a4.x, a4.y), fmaxf(a4.z, a4.w));
#pragma unroll
      for (int off = 16; off >= 1; off >>= 1)
        mx = fmaxf(mx, __shfl_xor(mx, off, 64));   // within 32-lane half-wave
      float s = (__expf(a4.x - mx) + __expf(a4.y - mx))
              + (__expf(a4.z - mx) + __expf(a4.w - mx));
#pragma unroll
      for (int off = 16; off >= 1; off >>= 1)
        s += __shfl_xor(s, off, 64);
      const float ls = mx + __logf(s);
      float* orow = out_g + (size_t)(node0 + row) * FDIM + li * 4;
      *(float4*)(orow) = make_float4(a4.x - ls, a4.y - ls, a4.z - ls, a4.w - ls);
    }
  }
}

extern "C" void kernel_launch(void* const* d_in, const int* in_sizes, int n_in,
                              void* d_out, int out_size, void* d_ws, size_t ws_size,
                              hipStream_t stream) {
  const float* x  = (const float*)d_in[0];
  const int*   ei = (const int*)d_in[1];     // int64 in reference -> int32 here
  const float* w1 = (const float*)d_in[2];
  const float* b1 = (const float*)d_in[3];
  const float* w2 = (const float*)d_in[4];
  const float* b2 = (const float*)d_in[5];
  float* out = (float*)d_out;

  const int E_ = in_sizes[1] / 2;
  const int PBLK = (E_ + 4095) / 4096;     // 157 edge blocks

  // ---- prep1: coarse partition only (binoff zero by invariant) ----
  prep1_kernel<<<PBLK, 512, 0, stream>>>(ei, E_);
  // ---- prep2: scan (first) + cast + wpack; restores binoff invariant ----
  prep2_kernel<<<NBIN + 625 + 8, 512, 0, stream>>>(x, w1, w2);

  // ---- layers: 1250 blocks x 8 waves x 1 node = 10000 exactly ----
  gin_layer_kernel<0><<<1250, 512, 0, stream>>>(b1, nullptr);
  gin_layer_kernel<1><<<1250, 512, 0, stream>>>(b2, out);
}

// Round 10
// 103.172 us; speedup vs baseline: 3.8491x; 1.0214x over previous
//
#include <hip/hip_runtime.h>
#include <cstdint>

#define NNODES 10000
#define FDIM 128
#define MAXDEG 192
#define NPB 40                             // nodes per bin (250 bins used)
#define NBIN 256
#define BINCAP 4096                        // entries per bin (mean ~2560, >30 sigma)
#define SENT16 0x27102710u                 // two u16 sentinels (10000 = zero row)

typedef _Float16 h2v  __attribute__((ext_vector_type(2)));
typedef _Float16 f16x8 __attribute__((ext_vector_type(8)));
typedef float    f32x4 __attribute__((ext_vector_type(4)));

// Module-owned scratch (BSS, zero at load) — no d_ws dependence.
// g_binoff invariant: zero at entry to every kernel_launch (BSS first call;
// prep2 scan blocks re-zero their own bin after consuming it, every call).
// g_cnt/g_bkt are FULLY REWRITTEN by prep2 every call; bucket rows are
// SENTINEL-PADDED to MAXDEG (sentinel = NNODES = zero feature row), so the
// gin layers load index registers UNPREDICATED (no deg dependency).
__device__ __align__(16)  int            g_binoff[NBIN];         // coarse-bin fill
__device__ __align__(16)  unsigned       g_binbuf[NBIN * BINCAP];// packed (rel,src), 4MB
__device__ __align__(16)  int            g_cnt[NNODES];          // degree (clamped)
__device__ __align__(16)  unsigned short g_bkt[NNODES * MAXDEG]; // u16 src lists, 3.84MB
__device__ __align__(256) unsigned g_xh [(NNODES + 1) * FDIM / 2]; // x  fp16x2
__device__ __align__(256) unsigned g_h1h[(NNODES + 1) * FDIM / 2]; // h1 fp16x2
__device__ __align__(16)  unsigned g_wf[2 * 8192];        // W1/W2 pre-packed B-frags

__device__ inline h2v as_h2(unsigned u) { return __builtin_bit_cast(h2v, u); }
__device__ inline unsigned as_u(h2v v) { return __builtin_bit_cast(unsigned, v); }
__device__ inline unsigned pack_f16x2(float a, float b) {
  h2v v; v[0] = (_Float16)a; v[1] = (_Float16)b;
  return as_u(v);
}
__device__ inline void vadd4(uint4& a, const uint4& b) {   // 4x v_pk_add_f16
  a.x = as_u(as_h2(a.x) + as_h2(b.x));
  a.y = as_u(as_h2(a.y) + as_h2(b.y));
  a.z = as_u(as_h2(a.z) + as_h2(b.z));
  a.w = as_u(as_h2(a.w) + as_h2(b.w));
}

// ---------------- prep1: coarse partition + cast + W pre-pack -------------
// Edge blocks (0..PBLK-1): block owns 4096 edges (8/thread). Bin by dst/40
// into 256 coarse bins: LDS rank -> ONE global atomic per (block,bin)
// reserves a contiguous run -> packed u32 (dst_rel<<16 | src) written as
// contiguous runs. Cast blocks (x -> fp16x2) and wpack blocks ride in the
// same grid: they depend only on x/w, and hide the edge pass's atomics.
__global__ __launch_bounds__(512) void prep1_kernel(
    const float* __restrict__ x, const int* __restrict__ ei,
    const float* __restrict__ w1, const float* __restrict__ w2,
    int E_, int PBLK) {
  const int bid = blockIdx.x, tid = threadIdx.x;
  if (bid < PBLK) {
    __shared__ int lcnt[NBIN], lbase[NBIN];
    if (tid < NBIN) lcnt[tid] = 0;
    __syncthreads();
    int dv[8], sv[8], rk[8], bn[8];
#pragma unroll
    for (int k = 0; k < 8; ++k) {          // coalesced dst+src loads
      int e = bid * 4096 + k * 512 + tid;
      dv[k] = (e < E_) ? ei[E_ + e] : -1;
      sv[k] = (e < E_) ? ei[e] : 0;
    }
#pragma unroll
    for (int k = 0; k < 8; ++k) {
      if (dv[k] >= 0) {
        bn[k] = (unsigned)dv[k] / NPB;     // const-div -> magic mul
        rk[k] = atomicAdd(&lcnt[bn[k]], 1);
      }
    }
    __syncthreads();
    if (tid < NBIN && lcnt[tid] > 0)
      lbase[tid] = atomicAdd(&g_binoff[tid], lcnt[tid]);
    __syncthreads();
#pragma unroll
    for (int k = 0; k < 8; ++k) {
      if (dv[k] >= 0) {
        int pos = lbase[bn[k]] + rk[k];
        if (pos < BINCAP)
          g_binbuf[bn[k] * BINCAP + pos] =
              ((unsigned)(dv[k] - bn[k] * NPB) << 16) | (unsigned)sv[k];
      }
    }
  } else if (bid < PBLK + 625) {
    int i = (bid - PBLK) * 512 + tid;      // < 320000 exactly
    if (i < NNODES * 32) {                 // float4 -> fp16x2 pair (16B->8B)
      float4 v = *(const float4*)(x + 4 * (size_t)i);
      uint2 o; o.x = pack_f16x2(v.x, v.y); o.y = pack_f16x2(v.z, v.w);
      *(uint2*)(g_xh + 2 * (size_t)i) = o;
    }
  } else {
    // pack W1/W2 into the exact MFMA B-fragment dword layout once.
    // entry s -> (nk = s>>6, sl = s&63), n = nk>>2, kc = nk&3,
    // kbase = kc*32 + (sl>>4)*8, f = n*16 + (sl&15).
    int idx = (bid - PBLK - 625) * 512 + tid;  // 0..4095
    if (idx < 4096) {
      const float* w = (idx >= 2048) ? w2 : w1;
      int s = idx & 2047;
      int sl = s & 63, nk = s >> 6;
      int n = nk >> 2, kc = nk & 3;
      int kbase = kc * 32 + (sl >> 4) * 8;
      int f = n * 16 + (sl & 15);
      unsigned d0 = pack_f16x2(w[(size_t)(kbase + 0) * FDIM + f],
                               w[(size_t)(kbase + 1) * FDIM + f]);
      unsigned d1 = pack_f16x2(w[(size_t)(kbase + 2) * FDIM + f],
                               w[(size_t)(kbase + 3) * FDIM + f]);
      unsigned d2 = pack_f16x2(w[(size_t)(kbase + 4) * FDIM + f],
                               w[(size_t)(kbase + 5) * FDIM + f]);
      unsigned d3 = pack_f16x2(w[(size_t)(kbase + 6) * FDIM + f],
                               w[(size_t)(kbase + 7) * FDIM + f]);
      *(uint4*)(g_wf + (idx >> 11) * 8192 + 4 * s) = make_uint4(d0, d1, d2, d3);
    }
  }
}

// ---------------- prep2: bin-local bucket build (256 blocks) --------------
// Block bid consumes ONLY bin bid (~2.5k packed entries, 10KB coalesced
// read), LDS-bins to SENTINEL-PREFILLED u16 buckets (rows padded to MAXDEG
// with 10000 = zero row), dense-coalesced writeout of g_cnt + g_bkt,
// restores the g_binoff zero invariant. 256 blocks = full-chip coverage
// (round-9's 128 scan blocks covered 50% of CUs); lbkt 15.4KB.
__global__ __launch_bounds__(512) void prep2_kernel() {
  __shared__ int lcnt[NPB];
  __shared__ __align__(16) unsigned short lbkt[NPB * MAXDEG];  // 15.4 KB

  const int bid = blockIdx.x, tid = threadIdx.x;
  const int lo = bid * NPB;
  const int nnr = NNODES - lo;
  const int nn = (nnr < 0) ? 0 : ((nnr < NPB) ? nnr : NPB);
  for (int i = tid; i < NPB; i += 512) lcnt[i] = 0;
  {                                        // sentinel pre-fill (pads rows)
    const uint4 sent = make_uint4(SENT16, SENT16, SENT16, SENT16);
    uint4* lb4 = (uint4*)lbkt;
    for (int i = tid; i < NPB * MAXDEG / 8; i += 512) lb4[i] = sent;
  }
  __syncthreads();

  int cnt = g_binoff[bid];
  if (cnt > BINCAP) cnt = BINCAP;
  const unsigned* buf = g_binbuf + (size_t)bid * BINCAP;
  for (int i = tid; i < cnt; i += 512) {
    unsigned p = buf[i];
    int rel = (int)(p >> 16);
    if (rel < nn) {
      int q = atomicAdd(&lcnt[rel], 1);
      if (q < MAXDEG) lbkt[rel * MAXDEG + q] = (unsigned short)(p & 0xffffu);
    }
  }
  __syncthreads();

  for (int i = tid; i < nn; i += 512)
    g_cnt[lo + i] = (lcnt[i] > MAXDEG) ? MAXDEG : lcnt[i];
  const int nq = nn * (MAXDEG / 8);        // uint4 = 8 u16; 24 per node
  const uint4* srcq = (const uint4*)lbkt;
  uint4* dstq = (uint4*)(g_bkt + (size_t)lo * MAXDEG);
  for (int i = tid; i < nq; i += 512) dstq[i] = srcq[i];
  if (tid == 0) g_binoff[bid] = 0;         // restore invariant
}

// ---------------- fused GIN layer: 8 nodes/block, 1 node/wave -------------
// Byte-identical to round 9 (proven best): unpredicated sentinel-padded
// index head, uniform 32-edge batches of 8 dwordx4 loads, quad-fold
// butterfly, register B-frags, 16x16x32_f16 MFMA (A rows 8..15 zero).
// MODE 0: relu -> g_h1h (packed fp16x2). MODE 1: log_softmax -> out_g (fp32).
template <int MODE>
__global__ __launch_bounds__(512) void gin_layer_kernel(
    const float* __restrict__ bvec,
    float* __restrict__ out_g) {
  const unsigned* __restrict__ xh = (MODE == 0) ? g_xh : g_h1h;

  __shared__ __align__(16) unsigned al[16 * 68];   // A tile 16 x 64 dw (+4 pad)
  __shared__ __align__(16) unsigned cfu[8 * 132];  // epilogue scratch (8 rows)

  const int tid = threadIdx.x;
  const int wave = tid >> 6, lane = tid & 63;
  const int quad = lane >> 4, m16 = lane & 15;
  const int node0 = blockIdx.x * 8;
  const int myn = node0 + wave;            // this wave's node

  // ---- head loads, all independent, issue immediately ----
  const unsigned short* nb16 = g_bkt + (size_t)myn * MAXDEG;
  int idxr[3];
#pragma unroll
  for (int r = 0; r < 3; ++r)
    idxr[r] = (int)nb16[r * 64 + lane];    // unpredicated (sentinel-padded)
  const int deg = g_cnt[myn];              // clamped to MAXDEG by prep2
  uint4 self4 = *(const uint4*)(xh + (size_t)myn * 64 + (m16 << 2));

  // ---- B-fragments straight to registers (L2-resident, pre-packed) ----
  uint4 bf[4];
  {
    const unsigned* wfp = g_wf + (MODE ? 8192 : 0);
#pragma unroll
    for (int kc = 0; kc < 4; ++kc)
      bf[kc] = *(const uint4*)(wfp + ((wave * 4 + kc) * 64 + lane) * 4);
  }
  const float bb = bvec[wave * 16 + m16];

  // zero A rows 8..15 (MFMA reads 16 rows; only 8 valid)
  for (int i2 = tid; i2 < 8 * 68; i2 += 512) al[8 * 68 + i2] = 0;

  // ---- gather: uniform full batches of 8 dwordx4 loads (32 edges) ----
  h2v a0 = as_h2(0u), a1 = as_h2(0u), a2 = as_h2(0u), a3 = as_h2(0u);
  const int nbat = (deg + 31) >> 5;        // ceil(deg/32), <= 6
  for (int bt = 0; bt < nbat; ++bt) {
    const int r = bt >> 1;
    const int src = (r == 0) ? idxr[0] : ((r == 1) ? idxr[1] : idxr[2]);
    const int base = (bt & 1) << 5;
    uint4 t[8];
#pragma unroll
    for (int k = 0; k < 8; ++k) {
      int e = __builtin_amdgcn_ds_bpermute((base + 4 * k + quad) << 2, src);
      t[k] = *(const uint4*)(xh + (unsigned)((e << 6) | (m16 << 2)));
    }
#pragma unroll
    for (int st2 = 1; st2 < 8; st2 <<= 1)
#pragma unroll
      for (int k = 0; k < 8; k += 2 * st2) vadd4(t[k], t[k + st2]);
    a0 += as_h2(t[0].x); a1 += as_h2(t[0].y);
    a2 += as_h2(t[0].z); a3 += as_h2(t[0].w);
  }

  // fold the 4 quad partials (xor-16 then xor-32 butterfly)
  int rr;
  rr = __shfl_xor((int)as_u(a0), 16, 64); a0 += as_h2((unsigned)rr);
  rr = __shfl_xor((int)as_u(a0), 32, 64); a0 += as_h2((unsigned)rr);
  rr = __shfl_xor((int)as_u(a1), 16, 64); a1 += as_h2((unsigned)rr);
  rr = __shfl_xor((int)as_u(a1), 32, 64); a1 += as_h2((unsigned)rr);
  rr = __shfl_xor((int)as_u(a2), 16, 64); a2 += as_h2((unsigned)rr);
  rr = __shfl_xor((int)as_u(a2), 32, 64); a2 += as_h2((unsigned)rr);
  rr = __shfl_xor((int)as_u(a3), 16, 64); a3 += as_h2((unsigned)rr);
  rr = __shfl_xor((int)as_u(a3), 32, 64); a3 += as_h2((unsigned)rr);
  // (1+eps)*x self term, added once after the fold
  a0 += as_h2(self4.x); a1 += as_h2(self4.y);
  a2 += as_h2(self4.z); a3 += as_h2(self4.w);
  if (quad == 0)
    *(uint4*)(al + wave * 68 + (m16 << 2)) =
        make_uint4(as_u(a0), as_u(a1), as_u(a2), as_u(a3));
  __syncthreads();                         // A tile visible to all waves

  // ---- MFMA: ntile n = wave, B from registers ----
  uint4 af[4];
#pragma unroll
  for (int kc = 0; kc < 4; ++kc)
    af[kc] = *(const uint4*)(al + m16 * 68 + kc * 16 + quad * 4);

  const int n = wave;
  f32x4 acc = {0.f, 0.f, 0.f, 0.f};
#pragma unroll
  for (int kc = 0; kc < 4; ++kc)
    acc = __builtin_amdgcn_mfma_f32_16x16x32_f16(
            __builtin_bit_cast(f16x8, af[kc]),
            __builtin_bit_cast(f16x8, bf[kc]), acc, 0, 0, 0);

  // ---- epilogue: D col=m16(+16n), row=quad*4+reg; rows 0..7 valid ----
  if (MODE == 0) {
    // relu + fp16 pack: rows padded to 136 halves for bank spread
    _Float16* ch = (_Float16*)cfu;
    const int f = n * 16 + m16;
    if (quad < 2) {
#pragma unroll
      for (int reg = 0; reg < 4; ++reg)
        ch[(quad * 4 + reg) * 136 + f] = (_Float16)fmaxf(acc[reg] + bb, 0.f);
    }
    __syncthreads();
    if (tid < 256) {
      const int row = tid >> 5, c2 = (tid & 31) * 2;
      uint2 v = *(const uint2*)(cfu + row * 68 + c2);
      *(uint2*)(&g_h1h[(size_t)(node0 + row) * 64 + c2]) = v;
    }
  } else {
    // log_softmax: vals to LDS fp32 (rows padded to 132 floats)
    float* cf = (float*)cfu;
    const int f = n * 16 + m16;
    if (quad < 2) {
#pragma unroll
      for (int reg = 0; reg < 4; ++reg)
        cf[(quad * 4 + reg) * 132 + f] = acc[reg] + bb;
    }
    __syncthreads();
    if (tid < 256) {
      const int row = tid >> 5, li = tid & 31;   // 32 threads per row
      const float* base = cf + row * 132 + li * 4;
      float4 a4 = *(const float4*)(base);
      float mx = fmaxf(fmaxf(a4.x, a4.y), fmaxf(a4.z, a4.w));
#pragma unroll
      for (int off = 16; off >= 1; off >>= 1)
        mx = fmaxf(mx, __shfl_xor(mx, off, 64));   // within 32-lane half-wave
      float s = (__expf(a4.x - mx) + __expf(a4.y - mx))
              + (__expf(a4.z - mx) + __expf(a4.w - mx));
#pragma unroll
      for (int off = 16; off >= 1; off >>= 1)
        s += __shfl_xor(s, off, 64);
      const float ls = mx + __logf(s);
      float* orow = out_g + (size_t)(node0 + row) * FDIM + li * 4;
      *(float4*)(orow) = make_float4(a4.x - ls, a4.y - ls, a4.z - ls, a4.w - ls);
    }
  }
}

extern "C" void kernel_launch(void* const* d_in, const int* in_sizes, int n_in,
                              void* d_out, int out_size, void* d_ws, size_t ws_size,
                              hipStream_t stream) {
  const float* x  = (const float*)d_in[0];
  const int*   ei = (const int*)d_in[1];     // int64 in reference -> int32 here
  const float* w1 = (const float*)d_in[2];
  const float* b1 = (const float*)d_in[3];
  const float* w2 = (const float*)d_in[4];
  const float* b2 = (const float*)d_in[5];
  float* out = (float*)d_out;

  const int E_ = in_sizes[1] / 2;
  const int PBLK = (E_ + 4095) / 4096;     // 157 edge blocks

  // ---- prep1: partition + cast + wpack (binoff zero by invariant) ----
  prep1_kernel<<<PBLK + 625 + 8, 512, 0, stream>>>(x, ei, w1, w2, E_, PBLK);
  // ---- prep2: bin-local bucket build, full-chip (restores invariant) ----
  prep2_kernel<<<NBIN, 512, 0, stream>>>();

  // ---- layers: 1250 blocks x 8 waves x 1 node = 10000 exactly ----
  gin_layer_kernel<0><<<1250, 512, 0, stream>>>(b1, nullptr);
  gin_layer_kernel<1><<<1250, 512, 0, stream>>>(b2, out);
}